// Round 1
// baseline (153.872 us; speedup 1.0000x reference)
//
#include <hip/hip_runtime.h>

#define BB   4
#define NN   8192
#define KK   16
#define CIN  64
#define COUTC 64
#define NCH  16
#define P    8            // points per block

__global__ __launch_bounds__(256) void ptconv_fused(
    const float* __restrict__ inp,       // [B,N,CIN]
    const float* __restrict__ points,    // [B,N,3]
    const float* __restrict__ next_pts,  // [B,N,3]
    const int*   __restrict__ indices,   // [B,N,K]
    const float* __restrict__ weight,    // [CIN,NC,COUT] -> [1024,64]
    const float* __restrict__ bias,      // [COUT]
    const float* __restrict__ centers,   // [3,NC] flat 48
    const float* __restrict__ l1w, const float* __restrict__ l1b,  // [48,32],[32]
    const float* __restrict__ l2w, const float* __restrict__ l2b,  // [32,16],[16]
    const float* __restrict__ l3w, const float* __restrict__ l3b,  // [16,16],[16]
    float* __restrict__ out)             // [B,N,COUT]
{
    const int t   = threadIdx.x;
    const int pt0 = blockIdx.x * P;      // first global point id in this block
    const int b   = pt0 / NN;
    const int n0  = pt0 % NN;
    (void)n0;

    __shared__ float s_A[3][32];         // folded layer-1 weights
    __shared__ float s_b1[32];           // folded layer-1 bias
    __shared__ float s_w2[32][16];
    __shared__ float s_b2[16];
    __shared__ float s_w3[16][16];
    __shared__ float s_b3[16];
    __shared__ int   s_idx[P][KK];
    __shared__ float s_nxt[P][3];
    __shared__ float s_h3[P][KK][NCH];   // 8 KB
    __shared__ float s_f[P][CIN*NCH];    // 32 KB
    __shared__ float s_red[4][P][COUTC]; // 8 KB

    // ---------------- setup: stage small weights, fold layer 1 ----------------
    if (t < 32) {
        float bb = l1b[t];
        float a0 = 0.f, a1 = 0.f, a2 = 0.f;
        #pragma unroll
        for (int c = 0; c < 16; ++c) {
            const float w0 = l1w[(c      ) * 32 + t];
            const float w1 = l1w[(16 + c ) * 32 + t];
            const float w2v = l1w[(32 + c) * 32 + t];
            a0 += w0; a1 += w1; a2 += w2v;
            bb -= centers[c] * w0 + centers[16 + c] * w1 + centers[32 + c] * w2v;
        }
        s_A[0][t] = a0; s_A[1][t] = a1; s_A[2][t] = a2; s_b1[t] = bb;
    }
    for (int i = t; i < 512; i += 256) ((float*)s_w2)[i] = l2w[i];
    if (t < 256) ((float*)s_w3)[t] = l3w[t];
    if (t < 16)  { s_b2[t] = l2b[t]; s_b3[t] = l3b[t]; }
    if (t < P * KK) ((int*)s_idx)[t] = indices[(size_t)pt0 * KK + t];
    if (t < P * 3)  ((float*)s_nxt)[t] = next_pts[(size_t)pt0 * 3 + t];
    __syncthreads();

    // ---------------- phase 1: MLP, one thread per (point, k) ----------------
    if (t < P * KK) {
        const int p = t >> 4, k = t & 15;
        const int id = s_idx[p][k];
        const float* pp = points + ((size_t)b * NN + id) * 3;
        const float px = pp[0] - s_nxt[p][0];
        const float py = pp[1] - s_nxt[p][1];
        const float pz = pp[2] - s_nxt[p][2];
        float h1[32];
        #pragma unroll
        for (int j = 0; j < 32; ++j)
            h1[j] = fmaxf(fmaf(px, s_A[0][j], fmaf(py, s_A[1][j], fmaf(pz, s_A[2][j], s_b1[j]))), 0.f);
        float h2[16];
        #pragma unroll
        for (int j = 0; j < 16; ++j) {
            float a = s_b2[j];
            #pragma unroll
            for (int i = 0; i < 32; ++i) a = fmaf(h1[i], s_w2[i][j], a);
            h2[j] = fmaxf(a, 0.f);
        }
        #pragma unroll
        for (int j = 0; j < 16; ++j) {
            float a = s_b3[j];
            #pragma unroll
            for (int i = 0; i < 16; ++i) a = fmaf(h2[i], s_w3[i][j], a);
            s_h3[p][k][j] = fmaxf(a, 0.f);
        }
    }
    __syncthreads();

    // ---------------- phase 2: f[p][cin][m] = sum_k feats*h3 ----------------
    // thread = (m = t&15, cin-quad g = t>>4)
    {
        const int m    = t & 15;
        const int g    = t >> 4;     // 0..15
        const int cin0 = g * 4;
        #pragma unroll
        for (int p = 0; p < P; ++p) {
            float a0 = 0.f, a1 = 0.f, a2 = 0.f, a3 = 0.f;
            #pragma unroll
            for (int k = 0; k < KK; ++k) {
                const float4 fv = *(const float4*)(inp + ((size_t)b * NN + s_idx[p][k]) * CIN + cin0);
                const float h = s_h3[p][k][m];
                a0 = fmaf(fv.x, h, a0);
                a1 = fmaf(fv.y, h, a1);
                a2 = fmaf(fv.z, h, a2);
                a3 = fmaf(fv.w, h, a3);
            }
            s_f[p][(cin0 + 0) * NCH + m] = a0;
            s_f[p][(cin0 + 1) * NCH + m] = a1;
            s_f[p][(cin0 + 2) * NCH + m] = a2;
            s_f[p][(cin0 + 3) * NCH + m] = a3;
        }
    }
    __syncthreads();

    // ---------------- phase 3: out[p][cout] = f_flat @ W / 16 + bias ----------------
    // thread = (cout = t&63, part = t>>6); each part sums 256 of the 1024 i's
    {
        const int cout = t & 63;
        const int part = t >> 6;
        float acc[P];
        #pragma unroll
        for (int p = 0; p < P; ++p) acc[p] = 0.f;
        const int i0 = part * 256;
        const float* wp = weight + (size_t)i0 * COUTC + cout;
        #pragma unroll 2
        for (int ii = 0; ii < 256; ii += 4) {
            const float w0 = wp[(ii + 0) * COUTC];
            const float w1 = wp[(ii + 1) * COUTC];
            const float w2v = wp[(ii + 2) * COUTC];
            const float w3v = wp[(ii + 3) * COUTC];
            #pragma unroll
            for (int p = 0; p < P; ++p) {
                const float4 f4 = *(const float4*)&s_f[p][i0 + ii];
                acc[p] = fmaf(f4.x, w0, fmaf(f4.y, w1, fmaf(f4.z, w2v, fmaf(f4.w, w3v, acc[p]))));
            }
        }
        #pragma unroll
        for (int p = 0; p < P; ++p) s_red[part][p][cout] = acc[p];
    }
    __syncthreads();

    // ---------------- final reduce + bias ----------------
    for (int o = t; o < P * COUTC; o += 256) {
        const int p = o >> 6, cout = o & 63;
        const float a = s_red[0][p][cout] + s_red[1][p][cout]
                      + s_red[2][p][cout] + s_red[3][p][cout];
        out[((size_t)pt0 + p) * COUTC + cout] = a * (1.0f / 16.0f) + bias[cout];
    }
}

extern "C" void kernel_launch(void* const* d_in, const int* in_sizes, int n_in,
                              void* d_out, int out_size, void* d_ws, size_t ws_size,
                              hipStream_t stream) {
    const float* inp      = (const float*)d_in[0];
    const float* points   = (const float*)d_in[1];
    const float* next_pts = (const float*)d_in[2];
    const int*   indices  = (const int*)  d_in[3];
    const float* weight   = (const float*)d_in[4];
    const float* bias     = (const float*)d_in[5];
    const float* centers  = (const float*)d_in[6];
    const float* l1w      = (const float*)d_in[7];
    const float* l1b      = (const float*)d_in[8];
    const float* l2w      = (const float*)d_in[9];
    const float* l2b      = (const float*)d_in[10];
    const float* l3w      = (const float*)d_in[11];
    const float* l3b      = (const float*)d_in[12];
    float* outp = (float*)d_out;

    const int n_points = BB * NN;           // 32768
    const int grid = n_points / P;          // 4096 blocks
    ptconv_fused<<<grid, 256, 0, stream>>>(inp, points, next_pts, indices,
                                           weight, bias, centers,
                                           l1w, l1b, l2w, l2b, l3w, l3b, outp);
}

// Round 2
// 88.147 us; speedup vs baseline: 1.7456x; 1.7456x over previous
//
#include <hip/hip_runtime.h>

#define BB    4
#define NN    8192
#define KK    16
#define CIN   64
#define COUTC 64
#define NCH   16
#define P     16           // points per block (= MFMA M-tile)

typedef short bf16x8 __attribute__((ext_vector_type(8)));
typedef float f32x4  __attribute__((ext_vector_type(4)));

__device__ __forceinline__ unsigned short f2bf_rne(float f) {
    unsigned int u = __builtin_bit_cast(unsigned int, f);
    u += 0x7fffu + ((u >> 16) & 1u);
    return (unsigned short)(u >> 16);
}

// Wt[cout][k'] bf16 with k' = m*64 + cin, scale 1/16 folded in.
__global__ __launch_bounds__(256) void prep_w(const float* __restrict__ W,
                                              unsigned short* __restrict__ Wt) {
    const int o    = blockIdx.x * 256 + threadIdx.x;   // 65536 total
    const int cout = o >> 10;
    const int kp   = o & 1023;
    const int m    = kp >> 6;
    const int cin  = kp & 63;
    const float v  = W[(cin * 16 + m) * 64 + cout] * (1.0f / 16.0f);
    Wt[o] = f2bf_rne(v);
}

__global__ __launch_bounds__(256, 2) void ptconv_fused(
    const float* __restrict__ inp,       // [B,N,CIN]
    const float* __restrict__ points,    // [B,N,3]
    const float* __restrict__ next_pts,  // [B,N,3]
    const int*   __restrict__ indices,   // [B,N,K]
    const unsigned short* __restrict__ Wt, // [COUT][1024] bf16 (prep)
    const float* __restrict__ bias,      // [COUT]
    const float* __restrict__ centers,   // [3,NC] flat 48
    const float* __restrict__ l1w, const float* __restrict__ l1b,  // [48,32],[32]
    const float* __restrict__ l2w, const float* __restrict__ l2b,  // [32,16],[16]
    const float* __restrict__ l3w, const float* __restrict__ l3b,  // [16,16],[16]
    float* __restrict__ out)             // [B,N,COUT]
{
    const int t    = threadIdx.x;
    const int lane = t & 63;
    const int w    = t >> 6;             // wave id 0..3
    const int pt0  = blockIdx.x * P;
    const int b    = pt0 >> 13;          // pt0 / NN

    __shared__ float s_A1[32][4];        // folded layer-1: a0,a1,a2,b'
    __shared__ float s_w2[32][16];
    __shared__ float s_w3[16][16];
    __shared__ float s_b2[16], s_b3[16];
    __shared__ int   s_idx[P][KK];
    __shared__ float s_nxt[P][3];
    __shared__ float s_h3[P][264];       // row: k*16 + ((m+k)&15), pad 8
    __shared__ unsigned short s_fb[P][1024]; // bf16 rows 2048B, XOR-swizzled

    // ---------------- setup ----------------
    if (t < 32) {
        float bb = l1b[t];
        float a0 = 0.f, a1 = 0.f, a2 = 0.f;
        #pragma unroll
        for (int c = 0; c < 16; ++c) {
            const float w0 = l1w[(c     ) * 32 + t];
            const float w1 = l1w[(16 + c) * 32 + t];
            const float w2v = l1w[(32 + c) * 32 + t];
            a0 += w0; a1 += w1; a2 += w2v;
            bb -= centers[c] * w0 + centers[16 + c] * w1 + centers[32 + c] * w2v;
        }
        s_A1[t][0] = a0; s_A1[t][1] = a1; s_A1[t][2] = a2; s_A1[t][3] = bb;
    }
    for (int i = t; i < 512; i += 256) ((float*)s_w2)[i] = l2w[i];
    if (t < 256) ((float*)s_w3)[t] = l3w[t];
    if (t < 16)  { s_b2[t] = l2b[t]; s_b3[t] = l3b[t]; }
    ((int*)s_idx)[t] = indices[(size_t)pt0 * KK + t];     // 256 = P*KK
    if (t < P * 3) ((float*)s_nxt)[t] = next_pts[(size_t)pt0 * 3 + t];
    __syncthreads();

    // ---------------- phase 1: MLP, thread = (p,k) ----------------
    {
        const int p = t >> 4, k = t & 15;
        const int id = s_idx[p][k];
        const float* pp = points + ((size_t)(b * NN + id)) * 3;
        const float px = pp[0] - s_nxt[p][0];
        const float py = pp[1] - s_nxt[p][1];
        const float pz = pp[2] - s_nxt[p][2];
        float h1[32];
        #pragma unroll
        for (int j = 0; j < 32; ++j) {
            const float4 a = *(const float4*)&s_A1[j][0];
            h1[j] = fmaxf(fmaf(px, a.x, fmaf(py, a.y, fmaf(pz, a.z, a.w))), 0.f);
        }
        float h2[16];
        #pragma unroll
        for (int j = 0; j < 16; ++j) h2[j] = s_b2[j];
        #pragma unroll
        for (int i = 0; i < 32; ++i) {
            const float4 q0 = *(const float4*)&s_w2[i][0];
            const float4 q1 = *(const float4*)&s_w2[i][4];
            const float4 q2 = *(const float4*)&s_w2[i][8];
            const float4 q3 = *(const float4*)&s_w2[i][12];
            h2[0]  = fmaf(h1[i], q0.x, h2[0]);  h2[1]  = fmaf(h1[i], q0.y, h2[1]);
            h2[2]  = fmaf(h1[i], q0.z, h2[2]);  h2[3]  = fmaf(h1[i], q0.w, h2[3]);
            h2[4]  = fmaf(h1[i], q1.x, h2[4]);  h2[5]  = fmaf(h1[i], q1.y, h2[5]);
            h2[6]  = fmaf(h1[i], q1.z, h2[6]);  h2[7]  = fmaf(h1[i], q1.w, h2[7]);
            h2[8]  = fmaf(h1[i], q2.x, h2[8]);  h2[9]  = fmaf(h1[i], q2.y, h2[9]);
            h2[10] = fmaf(h1[i], q2.z, h2[10]); h2[11] = fmaf(h1[i], q2.w, h2[11]);
            h2[12] = fmaf(h1[i], q3.x, h2[12]); h2[13] = fmaf(h1[i], q3.y, h2[13]);
            h2[14] = fmaf(h1[i], q3.z, h2[14]); h2[15] = fmaf(h1[i], q3.w, h2[15]);
        }
        #pragma unroll
        for (int j = 0; j < 16; ++j) h2[j] = fmaxf(h2[j], 0.f);
        float h3[16];
        #pragma unroll
        for (int j = 0; j < 16; ++j) h3[j] = s_b3[j];
        #pragma unroll
        for (int i = 0; i < 16; ++i) {
            const float4 q0 = *(const float4*)&s_w3[i][0];
            const float4 q1 = *(const float4*)&s_w3[i][4];
            const float4 q2 = *(const float4*)&s_w3[i][8];
            const float4 q3 = *(const float4*)&s_w3[i][12];
            h3[0]  = fmaf(h2[i], q0.x, h3[0]);  h3[1]  = fmaf(h2[i], q0.y, h3[1]);
            h3[2]  = fmaf(h2[i], q0.z, h3[2]);  h3[3]  = fmaf(h2[i], q0.w, h3[3]);
            h3[4]  = fmaf(h2[i], q1.x, h3[4]);  h3[5]  = fmaf(h2[i], q1.y, h3[5]);
            h3[6]  = fmaf(h2[i], q1.z, h3[6]);  h3[7]  = fmaf(h2[i], q1.w, h3[7]);
            h3[8]  = fmaf(h2[i], q2.x, h3[8]);  h3[9]  = fmaf(h2[i], q2.y, h3[9]);
            h3[10] = fmaf(h2[i], q2.z, h3[10]); h3[11] = fmaf(h2[i], q2.w, h3[11]);
            h3[12] = fmaf(h2[i], q3.x, h3[12]); h3[13] = fmaf(h2[i], q3.y, h3[13]);
            h3[14] = fmaf(h2[i], q3.z, h3[14]); h3[15] = fmaf(h2[i], q3.w, h3[15]);
        }
        // rotated write: position (m+k)&15 holds h3[m]  -> ~2-way conflicts
        #pragma unroll
        for (int m = 0; m < 16; ++m)
            s_h3[p][k * 16 + ((m + k) & 15)] = fmaxf(h3[m], 0.f);
    }
    __syncthreads();

    // ---------------- phase 2: f[p][cin][m], lane = cin ----------------
    {
        #pragma unroll
        for (int j = 0; j < 4; ++j) {
            const int p2 = w * 4 + j;
            float acc[16];
            #pragma unroll
            for (int m = 0; m < 16; ++m) acc[m] = 0.f;
            #pragma unroll
            for (int k = 0; k < 16; ++k) {
                const int id = s_idx[p2][k];
                const float fv = inp[((size_t)(b * NN + id)) * 64 + lane];
                const float* hr = &s_h3[p2][k * 16];
                float hv[16];
                #pragma unroll
                for (int q = 0; q < 4; ++q) {
                    const float4 qq = *(const float4*)(hr + q * 4);
                    hv[q * 4 + 0] = qq.x; hv[q * 4 + 1] = qq.y;
                    hv[q * 4 + 2] = qq.z; hv[q * 4 + 3] = qq.w;
                }
                #pragma unroll
                for (int m = 0; m < 16; ++m)
                    acc[m] = fmaf(fv, hv[(m + k) & 15], acc[m]);
            }
            // bf16 RNE + swizzled b16 writes: k' = m*64 + cin
            const unsigned int rowbase = (unsigned)p2 * 2048u;
            const unsigned int xr = (unsigned)(p2 & 7) << 4;
            char* fbb = (char*)s_fb;
            #pragma unroll
            for (int m = 0; m < 16; ++m) {
                const unsigned int off = (rowbase + (unsigned)(m * 64 + lane) * 2u) ^ xr;
                *(unsigned short*)(fbb + off) = f2bf_rne(acc[m]);
            }
        }
    }
    __syncthreads();

    // ---------------- phase 3: MFMA, wave w -> couts [w*16, w*16+16) ----------------
    {
        const int arow = lane & 15;      // A row = point ; B col = cout_local
        const int hi   = lane >> 4;
        const unsigned int abase = (unsigned)arow * 2048u + (unsigned)hi * 16u;
        const unsigned int xr    = (unsigned)(arow & 7) << 4;
        const unsigned short* wb = Wt + (size_t)(w * 16 + arow) * 1024 + hi * 8;
        const char* fbb = (const char*)s_fb;
        f32x4 acc = {0.f, 0.f, 0.f, 0.f};
        #pragma unroll
        for (int kk = 0; kk < 32; ++kk) {
            const bf16x8 av = *(const bf16x8*)(fbb + ((abase + (unsigned)kk * 64u) ^ xr));
            const bf16x8 bv = *(const bf16x8*)(wb + kk * 32);
            acc = __builtin_amdgcn_mfma_f32_16x16x32_bf16(av, bv, acc, 0, 0, 0);
        }
        const float bv = bias[w * 16 + arow];
        #pragma unroll
        for (int r = 0; r < 4; ++r) {
            const int prow = hi * 4 + r;
            out[((size_t)(pt0 + prow)) * 64 + w * 16 + arow] = acc[r] + bv;
        }
    }
}

extern "C" void kernel_launch(void* const* d_in, const int* in_sizes, int n_in,
                              void* d_out, int out_size, void* d_ws, size_t ws_size,
                              hipStream_t stream) {
    const float* inp      = (const float*)d_in[0];
    const float* points   = (const float*)d_in[1];
    const float* next_pts = (const float*)d_in[2];
    const int*   indices  = (const int*)  d_in[3];
    const float* weight   = (const float*)d_in[4];
    const float* bias     = (const float*)d_in[5];
    const float* centers  = (const float*)d_in[6];
    const float* l1w      = (const float*)d_in[7];
    const float* l1b      = (const float*)d_in[8];
    const float* l2w      = (const float*)d_in[9];
    const float* l2b      = (const float*)d_in[10];
    const float* l3w      = (const float*)d_in[11];
    const float* l3b      = (const float*)d_in[12];
    float* outp = (float*)d_out;
    unsigned short* Wt = (unsigned short*)d_ws;   // 65536 bf16 = 128 KB

    prep_w<<<256, 256, 0, stream>>>(weight, Wt);

    const int grid = (BB * NN) / P;               // 2048 blocks
    ptconv_fused<<<grid, 256, 0, stream>>>(inp, points, next_pts, indices,
                                           Wt, bias, centers,
                                           l1w, l1b, l2w, l2b, l3w, l3b, outp);
}